// Round 3
// baseline (413.752 us; speedup 1.0000x reference)
//
#include <hip/hip_runtime.h>

// Problem constants (fixed by the reference)
#define B_   2
#define DZ   41
#define HY   400
#define WX   352
#define NVOX 40000
#define PD   43      // DZ+2
#define PH   402     // HY+2
#define PW   354     // WX+2
#define DO_  21
#define HO_  200
#define WO_  176
#define C1   128
#define GRID_CELLS (B_*PD*PH*PW)        // 12,238,488
#define OUT_POS    (B_*DO_*HO_*WO_)     // 1,478,400 (divisible by 8)

// dtypes (established rounds 1-2): ALL float tensors are FLOAT32, output is
// FLOAT32. coors is int32. Round-1 inf = f32 read as bf16; round-2 error
// 0.0605 = only half of the f32 out buffer written (bf16-packed), second
// half zero. The "(bf16" in the harness assert label is hardcoded text.

// ---- build padded dense grid of (voxel id + 1), 0 = empty ----
__global__ void k_build(const int* __restrict__ coors, unsigned short* __restrict__ grid) {
    int n = blockIdx.x * blockDim.x + threadIdx.x;
    if (n >= NVOX) return;
    int b = coors[4*n+0], z = coors[4*n+1], y = coors[4*n+2], x = coors[4*n+3];
    grid[((b*PD + z+1)*PH + y+1)*PW + x+1] = (unsigned short)(n + 1);
}

// ---- precompute 27-neighbor table (used by both subm convs) ----
__global__ void k_nbr(const int* __restrict__ coors, const unsigned short* __restrict__ grid,
                      int* __restrict__ nbr) {
    int i = blockIdx.x * blockDim.x + threadIdx.x;
    if (i >= NVOX * 27) return;
    int n = i / 27, k = i % 27;
    int b = coors[4*n+0], z = coors[4*n+1], y = coors[4*n+2], x = coors[4*n+3];
    int dz = k / 9, dy = (k / 3) % 3, dx = k % 3;
    // padded grid: set at +1; lookup at z+dz, dz in [0,3) -> always in bounds
    nbr[i] = (int)grid[((b*PD + z+dz)*PH + y+dy)*PW + x+dx] - 1;
}

// ---- subm conv 1: 128 -> 16, ReLU, fp32 out ----
// block = 256 threads = 16 voxels x 16 out-channels
__global__ void k_subm1(const float* __restrict__ feat,
                        const float* __restrict__ W1,
                        const int* __restrict__ nbr, float* __restrict__ x1) {
    __shared__ int s_nbr[16][27];
    int base = blockIdx.x * 16;
    for (int i = threadIdx.x; i < 16*27; i += 256) {
        int v = i / 27, k = i % 27;
        int n = base + v;
        s_nbr[v][k] = (n < NVOX) ? nbr[n*27 + k] : -1;
    }
    __syncthreads();
    int v = threadIdx.x >> 4, d = threadIdx.x & 15;
    int n = base + v;
    if (n >= NVOX) return;
    float acc = 0.f;
    for (int k = 0; k < 27; ++k) {
        int idx = s_nbr[v][k];
        if (idx < 0) continue;
        const float* f = feat + (size_t)idx * C1;
        const float* w = W1 + k * C1 * 16 + d;
        #pragma unroll 8
        for (int c = 0; c < C1; ++c)
            acc += f[c] * w[c * 16];
    }
    x1[n*16 + d] = fmaxf(acc, 0.f);
}

// ---- subm conv 2: 16 -> 16, ReLU, fp32 out ----
__global__ void k_subm2(const float* __restrict__ x1,
                        const float* __restrict__ W2,
                        const int* __restrict__ nbr, float* __restrict__ x2) {
    __shared__ int   s_nbr[16][27];
    __shared__ float s_w2[27*16*16];
    for (int i = threadIdx.x; i < 27*16*16; i += 256) s_w2[i] = W2[i];
    int base = blockIdx.x * 16;
    for (int i = threadIdx.x; i < 16*27; i += 256) {
        int v = i / 27, k = i % 27;
        int n = base + v;
        s_nbr[v][k] = (n < NVOX) ? nbr[n*27 + k] : -1;
    }
    __syncthreads();
    int v = threadIdx.x >> 4, d = threadIdx.x & 15;
    int n = base + v;
    if (n >= NVOX) return;
    float acc = 0.f;
    for (int k = 0; k < 27; ++k) {
        int idx = s_nbr[v][k];
        if (idx < 0) continue;
        const float* xp = x1 + idx * 16;
        const float* w  = s_w2 + k * 256 + d;
        #pragma unroll
        for (int c = 0; c < 16; ++c) acc += xp[c] * w[c * 16];
    }
    x2[n*16 + d] = fmaxf(acc, 0.f);
}

// ---- stride-2 sparse conv 16 -> 32, gather formulation, ReLU, f32 out ----
// block = 256 threads = 8 output positions x 32 channels
__global__ void k_conv(const float* __restrict__ x2,
                       const float* __restrict__ W3,
                       const unsigned short* __restrict__ grid,
                       float* __restrict__ out) {
    __shared__ int s_nbr[8][27];
    __shared__ int s_any;
    if (threadIdx.x == 0) s_any = 0;
    __syncthreads();
    int pbase = blockIdx.x * 8;
    for (int i = threadIdx.x; i < 8*27; i += 256) {
        int v = i / 27, k = i % 27;
        int p = pbase + v;
        int b    = p / (DO_*HO_*WO_);
        int rem  = p - b * (DO_*HO_*WO_);
        int pz   = rem / (HO_*WO_);
        int rem2 = rem - pz * (HO_*WO_);
        int py   = rem2 / WO_;
        int px   = rem2 - py * WO_;
        int dz = k / 9, dy = (k / 3) % 3, dx = k % 3;
        // input padded coord = 2*p + d; max = 2*(Do-1)+2 = PD-1 -> no bounds check
        int idx = (int)grid[((b*PD + 2*pz+dz)*PH + 2*py+dy)*PW + 2*px+dx] - 1;
        s_nbr[v][k] = idx;
        if (idx >= 0) atomicOr(&s_any, 1);
    }
    __syncthreads();
    if (!s_any) {
        // block covers 8 pos x 32 ch = 256 contiguous f32 -> one float per thread
        float* po = out + (size_t)pbase * 32;
        po[threadIdx.x] = 0.f;
        return;
    }
    int v = threadIdx.x >> 5, d = threadIdx.x & 31;
    int p = pbase + v;
    float acc = 0.f;
    for (int k = 0; k < 27; ++k) {
        int idx = s_nbr[v][k];
        if (idx < 0) continue;
        const float* xp = x2 + idx * 16;
        const float* w  = W3 + k * 16 * 32 + d;
        #pragma unroll
        for (int c = 0; c < 16; ++c) acc += xp[c] * w[c * 32];
    }
    out[(size_t)p * 32 + d] = fmaxf(acc, 0.f);
}

extern "C" void kernel_launch(void* const* d_in, const int* in_sizes, int n_in,
                              void* d_out, int out_size, void* d_ws, size_t ws_size,
                              hipStream_t stream) {
    const float* feat  = (const float*)d_in[0];  // f32 (N,128)
    const int*   coors = (const int*)d_in[1];    // int32 (N,4)
    const float* W1    = (const float*)d_in[2];  // f32 (27,128,16)
    const float* W2    = (const float*)d_in[3];  // f32 (27,16,16)
    const float* W3    = (const float*)d_in[4];  // f32 (27,16,32)
    float* out = (float*)d_out;                  // f32 (2,21,200,176,32)

    char* ws = (char*)d_ws;
    size_t off = 0;
    unsigned short* grid = (unsigned short*)(ws + off);
    off += (((size_t)GRID_CELLS*2) + 255) & ~(size_t)255;
    int* nbr  = (int*)(ws + off); off += (((size_t)NVOX*27*4)   + 255) & ~(size_t)255;
    float* x1 = (float*)(ws + off); off += (((size_t)NVOX*16*4) + 255) & ~(size_t)255;
    float* x2 = (float*)(ws + off);

    hipMemsetAsync(grid, 0x00, (size_t)GRID_CELLS * 2, stream);   // grid = 0 (empty)
    k_build<<<(NVOX + 255) / 256, 256, 0, stream>>>(coors, grid);
    k_nbr<<<(NVOX*27 + 255) / 256, 256, 0, stream>>>(coors, grid, nbr);
    k_subm1<<<(NVOX + 15) / 16, 256, 0, stream>>>(feat, W1, nbr, x1);
    k_subm2<<<(NVOX + 15) / 16, 256, 0, stream>>>(x1, W2, nbr, x2);
    k_conv<<<OUT_POS / 8, 256, 0, stream>>>(x2, W3, grid, out);
}

// Round 4
// 304.520 us; speedup vs baseline: 1.3587x; 1.3587x over previous
//
#include <hip/hip_runtime.h>

// Problem constants (fixed by the reference)
#define B_   2
#define DZ   41
#define HY   400
#define WX   352
#define NVOX 40000
#define PD   43      // DZ+2
#define PH   402     // HY+2
#define PW   354     // WX+2
#define DO_  21
#define HO_  200
#define WO_  176
#define C1   128
#define GRID_CELLS (B_*PD*PH*PW)        // 12,238,488
#define OUT_POS    (B_*DO_*HO_*WO_)     // 1,478,400

// dtypes (established rounds 1-3): all float tensors f32 in AND out; coors int32.
// Round 3 baseline (gather k_conv): 413.8 us total, k_conv 182.5 us VALU-bound.
// Round 4: stride-2 conv as SCATTER from 40k voxels (parity-enumerated taps,
// ~135k pairs) + memset + idempotent relu pass.

// ---- build padded dense grid of (voxel id + 1), 0 = empty ----
__global__ void k_build(const int* __restrict__ coors, unsigned short* __restrict__ grid) {
    int n = blockIdx.x * blockDim.x + threadIdx.x;
    if (n >= NVOX) return;
    int b = coors[4*n+0], z = coors[4*n+1], y = coors[4*n+2], x = coors[4*n+3];
    grid[((b*PD + z+1)*PH + y+1)*PW + x+1] = (unsigned short)(n + 1);
}

// ---- precompute 27-neighbor table (used by both subm convs) ----
__global__ void k_nbr(const int* __restrict__ coors, const unsigned short* __restrict__ grid,
                      int* __restrict__ nbr) {
    int i = blockIdx.x * blockDim.x + threadIdx.x;
    if (i >= NVOX * 27) return;
    int n = i / 27, k = i % 27;
    int b = coors[4*n+0], z = coors[4*n+1], y = coors[4*n+2], x = coors[4*n+3];
    int dz = k / 9, dy = (k / 3) % 3, dx = k % 3;
    nbr[i] = (int)grid[((b*PD + z+dz)*PH + y+dy)*PW + x+dx] - 1;
}

// ---- subm conv 1: 128 -> 16, ReLU, fp32 out ----
__global__ void k_subm1(const float* __restrict__ feat,
                        const float* __restrict__ W1,
                        const int* __restrict__ nbr, float* __restrict__ x1) {
    __shared__ int s_nbr[16][27];
    int base = blockIdx.x * 16;
    for (int i = threadIdx.x; i < 16*27; i += 256) {
        int v = i / 27, k = i % 27;
        int n = base + v;
        s_nbr[v][k] = (n < NVOX) ? nbr[n*27 + k] : -1;
    }
    __syncthreads();
    int v = threadIdx.x >> 4, d = threadIdx.x & 15;
    int n = base + v;
    if (n >= NVOX) return;
    float acc = 0.f;
    for (int k = 0; k < 27; ++k) {
        int idx = s_nbr[v][k];
        if (idx < 0) continue;
        const float* f = feat + (size_t)idx * C1;
        const float* w = W1 + k * C1 * 16 + d;
        #pragma unroll 8
        for (int c = 0; c < C1; ++c)
            acc += f[c] * w[c * 16];
    }
    x1[n*16 + d] = fmaxf(acc, 0.f);
}

// ---- subm conv 2: 16 -> 16, ReLU, fp32 out ----
__global__ void k_subm2(const float* __restrict__ x1,
                        const float* __restrict__ W2,
                        const int* __restrict__ nbr, float* __restrict__ x2) {
    __shared__ int   s_nbr[16][27];
    __shared__ float s_w2[27*16*16];
    for (int i = threadIdx.x; i < 27*16*16; i += 256) s_w2[i] = W2[i];
    int base = blockIdx.x * 16;
    for (int i = threadIdx.x; i < 16*27; i += 256) {
        int v = i / 27, k = i % 27;
        int n = base + v;
        s_nbr[v][k] = (n < NVOX) ? nbr[n*27 + k] : -1;
    }
    __syncthreads();
    int v = threadIdx.x >> 4, d = threadIdx.x & 15;
    int n = base + v;
    if (n >= NVOX) return;
    float acc = 0.f;
    for (int k = 0; k < 27; ++k) {
        int idx = s_nbr[v][k];
        if (idx < 0) continue;
        const float* xp = x1 + idx * 16;
        const float* w  = s_w2 + k * 256 + d;
        #pragma unroll
        for (int c = 0; c < 16; ++c) acc += xp[c] * w[c * 16];
    }
    x2[n*16 + d] = fmaxf(acc, 0.f);
}

// ---- valid downsample taps for one axis, from PADDED input coord ----
// ref: o = pcoord - doff (doff in 0..2), valid iff o even and 0 <= o/2 < outdim.
// pcoord >= 1; odd  -> doff=1 only, p=(pcoord-1)/2 always in range.
//             even -> doff=0 (p=h, check <outdim) and doff=2 (p=h-1, h>=1 always).
__device__ __forceinline__ int axis_taps(int pcoord, int outdim, int* ds, int* ps) {
    if (pcoord & 1) { ds[0] = 1; ps[0] = pcoord >> 1; return 1; }
    int h = pcoord >> 1, nu = 0;
    if (h < outdim) { ds[nu] = 0; ps[nu] = h; nu++; }
    ds[nu] = 2; ps[nu] = h - 1; nu++;
    return nu;
}

// ---- stride-2 conv 16 -> 32 as scatter: block = 8 voxels x 32 channels ----
__global__ void k_scatter(const float* __restrict__ x2,
                          const float* __restrict__ W3,
                          const int* __restrict__ coors,
                          float* __restrict__ out) {
    int v = threadIdx.x >> 5, d = threadIdx.x & 31;
    int n = blockIdx.x * 8 + v;
    if (n >= NVOX) return;
    int b  = coors[4*n+0];
    int zp = coors[4*n+1] + 1, yp = coors[4*n+2] + 1, xp = coors[4*n+3] + 1;
    int dz[2], pz[2], dy[2], py[2], dx[2], px[2];
    int nz = axis_taps(zp, DO_, dz, pz);
    int ny = axis_taps(yp, HO_, dy, py);
    int nx = axis_taps(xp, WO_, dx, px);
    const float4* xr = (const float4*)(x2 + (size_t)n * 16);
    float r[16];
    *(float4*)(r + 0)  = xr[0];
    *(float4*)(r + 4)  = xr[1];
    *(float4*)(r + 8)  = xr[2];
    *(float4*)(r + 12) = xr[3];
    int bofs = b * (DO_*HO_*WO_);
    for (int iz = 0; iz < nz; ++iz)
        for (int iy = 0; iy < ny; ++iy)
            for (int ix = 0; ix < nx; ++ix) {
                int k = dz[iz]*9 + dy[iy]*3 + dx[ix];
                int p = bofs + (pz[iz]*HO_ + py[iy])*WO_ + px[ix];
                const float* w = W3 + k*512 + d;   // W3[k][c][d], stride 32 over c
                float acc = 0.f;
                #pragma unroll
                for (int c = 0; c < 16; ++c) acc += r[c] * w[c * 32];
                atomicAdd(out + (size_t)p * 32 + d, acc);
            }
}

// ---- idempotent ReLU over touched positions (duplicates are safe: all adds
// completed in the prior dispatch; concurrent relus write the same value) ----
__global__ void k_relu(const int* __restrict__ coors, float* __restrict__ out) {
    int v = threadIdx.x >> 5, d = threadIdx.x & 31;
    int n = blockIdx.x * 8 + v;
    if (n >= NVOX) return;
    int b  = coors[4*n+0];
    int zp = coors[4*n+1] + 1, yp = coors[4*n+2] + 1, xp = coors[4*n+3] + 1;
    int dz[2], pz[2], dy[2], py[2], dx[2], px[2];
    int nz = axis_taps(zp, DO_, dz, pz);
    int ny = axis_taps(yp, HO_, dy, py);
    int nx = axis_taps(xp, WO_, dx, px);
    int bofs = b * (DO_*HO_*WO_);
    for (int iz = 0; iz < nz; ++iz)
        for (int iy = 0; iy < ny; ++iy)
            for (int ix = 0; ix < nx; ++ix) {
                int p = bofs + (pz[iz]*HO_ + py[iy])*WO_ + px[ix];
                size_t o = (size_t)p * 32 + d;
                out[o] = fmaxf(out[o], 0.f);
            }
}

extern "C" void kernel_launch(void* const* d_in, const int* in_sizes, int n_in,
                              void* d_out, int out_size, void* d_ws, size_t ws_size,
                              hipStream_t stream) {
    const float* feat  = (const float*)d_in[0];  // f32 (N,128)
    const int*   coors = (const int*)d_in[1];    // int32 (N,4)
    const float* W1    = (const float*)d_in[2];  // f32 (27,128,16)
    const float* W2    = (const float*)d_in[3];  // f32 (27,16,16)
    const float* W3    = (const float*)d_in[4];  // f32 (27,16,32)
    float* out = (float*)d_out;                  // f32 (2,21,200,176,32)

    char* ws = (char*)d_ws;
    size_t off = 0;
    unsigned short* grid = (unsigned short*)(ws + off);
    off += (((size_t)GRID_CELLS*2) + 255) & ~(size_t)255;
    int* nbr  = (int*)(ws + off); off += (((size_t)NVOX*27*4)   + 255) & ~(size_t)255;
    float* x1 = (float*)(ws + off); off += (((size_t)NVOX*16*4) + 255) & ~(size_t)255;
    float* x2 = (float*)(ws + off);

    hipMemsetAsync(grid, 0x00, (size_t)GRID_CELLS * 2, stream);     // grid = 0 (empty)
    hipMemsetAsync(out, 0x00, (size_t)out_size * sizeof(float), stream);
    k_build<<<(NVOX + 255) / 256, 256, 0, stream>>>(coors, grid);
    k_nbr<<<(NVOX*27 + 255) / 256, 256, 0, stream>>>(coors, grid, nbr);
    k_subm1<<<(NVOX + 15) / 16, 256, 0, stream>>>(feat, W1, nbr, x1);
    k_subm2<<<(NVOX + 15) / 16, 256, 0, stream>>>(x1, W2, nbr, x2);
    k_scatter<<<(NVOX + 7) / 8, 256, 0, stream>>>(x2, W3, coors, out);
    k_relu<<<(NVOX + 7) / 8, 256, 0, stream>>>(coors, out);
}